// Round 16
// baseline (166.773 us; speedup 1.0000x reference)
//
#include <hip/hip_runtime.h>
#include <hip/hip_bf16.h>

// Problem constants
constexpr int BATCH = 2, SEQ = 2048, HDIM = 1024, NHEADS = 16, HEADD = 64;
constexpr int MROWS = BATCH * SEQ;            // 4096
// fold attention scale and exp->exp2 conversion: c = 0.125 / ln(2)
constexpr float QSCALE = 0.18033688011112042f;

typedef short short8  __attribute__((ext_vector_type(8)));
typedef float f32x4   __attribute__((ext_vector_type(4)));
typedef float f32x16  __attribute__((ext_vector_type(16)));
typedef int   int4v   __attribute__((ext_vector_type(4)));
typedef unsigned short ushort4v __attribute__((ext_vector_type(4)));

static __device__ __forceinline__ short f2bf(float f) {
    __hip_bfloat16 h = __float2bfloat16(f);
    return *reinterpret_cast<short*>(&h);
}

static __device__ __forceinline__ int cvt_pk_bf16(float a, float b) {
    int r;
    asm("v_cvt_pk_bf16_f32 %0, %1, %2" : "=v"(r) : "v"(a), "v"(b));
    return r;
}

static __device__ __forceinline__ float bfbits2f(unsigned short u) {
    return __builtin_bit_cast(float, (unsigned int)u << 16);
}

static __device__ __forceinline__ void gload_lds16(const void* g, void* l) {
    __builtin_amdgcn_global_load_lds(
        (const __attribute__((address_space(1))) unsigned int*)g,
        (__attribute__((address_space(3))) unsigned int*)l, 16, 0, 0);
}

// swizzle slot function: row-periodic mod 32, involution on 16B slots
static __device__ __forceinline__ int swz(int row) {
    return (((row & 7) ^ ((row >> 3) & 3))) << 4;
}

// ---------------- conversions: f32 -> bf16, all 7 tensors, one launch ----------------
__global__ void cvt_all_kernel(const float* __restrict__ q, const float* __restrict__ k,
                               const float* __restrict__ v, const float* __restrict__ w0,
                               const float* __restrict__ w1, const float* __restrict__ w2,
                               const float* __restrict__ w3,
                               short* __restrict__ xq, short* __restrict__ xk,
                               short* __restrict__ xv, short* __restrict__ o0,
                               short* __restrict__ o1, short* __restrict__ o2,
                               short* __restrict__ o3, int n4x, int n4w) {
    int i = blockIdx.x * blockDim.x + threadIdx.x;
    const int stride = gridDim.x * blockDim.x;
    const int total = 3 * n4x + 4 * n4w;
    for (; i < total; i += stride) {
        const float* in; short* out; int j = i;
        if (j < 3 * n4x) {
            if (j >= 2 * n4x)      { in = v; out = xv; j -= 2 * n4x; }
            else if (j >= n4x)     { in = k; out = xk; j -= n4x; }
            else                   { in = q; out = xq; }
        } else {
            j -= 3 * n4x;
            if (j >= 3 * n4w)      { in = w3; out = o3; j -= 3 * n4w; }
            else if (j >= 2 * n4w) { in = w2; out = o2; j -= 2 * n4w; }
            else if (j >= n4w)     { in = w1; out = o1; j -= n4w; }
            else                   { in = w0; out = o0; }
        }
        const float4 val = reinterpret_cast<const float4*>(in)[j];
        short4 o;
        o.x = f2bf(val.x); o.y = f2bf(val.y); o.z = f2bf(val.z); o.w = f2bf(val.w);
        reinterpret_cast<short4*>(out)[j] = o;
    }
}

// ---------------- mask dtype probe ----------------
__global__ void detect_mask_kernel(const unsigned int* __restrict__ m, int* flag) {
    const int tid = threadIdx.x;
    int gt1 = 0, isf = 0;
    for (int i = 0; i < 4; ++i) {
        unsigned int wv = m[tid + 256 * i];
        if (wv > 1u) gt1 = 1;
        if (wv == 0x3F800000u) isf = 1;
    }
    __shared__ int s_gt1, s_isf;
    if (tid == 0) { s_gt1 = 0; s_isf = 0; }
    __syncthreads();
    if (gt1) atomicOr(&s_gt1, 1);
    if (isf) atomicOr(&s_isf, 1);
    __syncthreads();
    if (tid == 0) flag[0] = s_gt1 ? (s_isf ? 2 : 1) : 0;
}

// ---------------- fuse_rel body (LDS tile transpose, coalesced) ----------------
// rT short4-index [(b*512 + kv/4)*2048 + q], component j = kv%4:
//   rT[...][j] = mask[b][q][kv] ? bf16(rel[b][q][kv] * QSCALE) : bf16(-1e30f)
// Tile 64 q x 256 kv; needs 16640 shorts of LDS.
static __device__ __forceinline__
void fuse_rel_body(short* tile, int bid, const float* __restrict__ rel,
                   const void* __restrict__ mask, int f, short* __restrict__ rT) {
    constexpr int QT = 64, KT = 256;
    constexpr int STRIDE = KT + 4;            // bf16 elements; +8B pad
    const int b   = bid >> 8;                 // 256 tiles per batch
    const int t8  = (bid >> 5) & 7;           // kv-tile 0..7
    const int t32 = bid & 31;                 // q-tile 0..31
    const int q0  = t32 * QT;
    const int kv0 = t8 * KT;
    const int tid = threadIdx.x;

    // phase 1: coalesced read -> masked bf16 -> LDS
    const int c4 = tid & 63;
    const int r4 = tid >> 6;
    #pragma unroll 4
    for (int it = 0; it < 16; ++it) {
        const int row = it * 4 + r4;
        const long src = ((long)(b * 2048 + q0 + row)) * 2048 + kv0 + c4 * 4;
        const float4 v = *reinterpret_cast<const float4*>(rel + src);
        bool mk[4];
        if (f == 1) {
            const unsigned int mw =
                *reinterpret_cast<const unsigned int*>((const unsigned char*)mask + src);
            mk[0] = (mw & 0xffu) != 0;       mk[1] = (mw & 0xff00u) != 0;
            mk[2] = (mw & 0xff0000u) != 0;   mk[3] = (mw & 0xff000000u) != 0;
        } else if (f == 0) {
            const int4 mi = *reinterpret_cast<const int4*>((const int*)mask + src);
            mk[0] = mi.x != 0; mk[1] = mi.y != 0; mk[2] = mi.z != 0; mk[3] = mi.w != 0;
        } else {
            const float4 mf = *reinterpret_cast<const float4*>((const float*)mask + src);
            mk[0] = mf.x != 0.0f; mk[1] = mf.y != 0.0f;
            mk[2] = mf.z != 0.0f; mk[3] = mf.w != 0.0f;
        }
        short4 o;
        o.x = f2bf(mk[0] ? v.x * QSCALE : -1e30f);
        o.y = f2bf(mk[1] ? v.y * QSCALE : -1e30f);
        o.z = f2bf(mk[2] ? v.z * QSCALE : -1e30f);
        o.w = f2bf(mk[3] ? v.w * QSCALE : -1e30f);
        *reinterpret_cast<short4*>(&tile[row * STRIDE + c4 * 4]) = o;
    }
    __syncthreads();

    // phase 2: transposed coalesced write of 64 planes (p = kv>>2)
    const int qq  = tid & 63;
    const int p4r = tid >> 6;
    #pragma unroll 4
    for (int it = 0; it < 16; ++it) {
        const int pl = it * 4 + p4r;
        const short4 o = *reinterpret_cast<const short4*>(&tile[qq * STRIDE + pl * 4]);
        *reinterpret_cast<short4*>(
            rT + (((long)(b * 512 + (kv0 >> 2) + pl)) * 2048 + q0 + qq) * 4) = o;
    }
}

__global__ __launch_bounds__(256)
void fuse_rel_kernel(const float* __restrict__ rel, const void* __restrict__ mask,
                     const int* __restrict__ flag, short* __restrict__ rT) {
    __shared__ short tile[16640];
    fuse_rel_body(tile, blockIdx.x, rel, mask, flag[0], rT);
}

// ===== GEMM core (128xBN tile, BK=64, single-buffer 2-phase, XOR-swizzled LDS) =====
// smem: >= (128 + BN) * 64 shorts.
template<int BN, typename EPI>
static __device__ __forceinline__
void gemm_core(short* smem, const short* A, const short* Bw, int K, int m0, int n0, EPI epi) {
    constexpr int NFRAG = BN / 32;        // n fragments per wave
    short* As = smem;
    short* Bs = smem + 128 * 64;
    const int tid  = threadIdx.x;
    const int lane = tid & 63;
    const int w    = tid >> 6;
    const int lo   = lane & 15, hi = lane >> 4;
    const int wm   = w >> 1, wn = w & 1;

    f32x4 acc[4][NFRAG] = {};

    // staging: pre-swizzled global source column -> linear LDS dest
    const int arow  = tid >> 3;                 // 0..31
    const int acolb = (tid & 7) * 16;           // byte col in 128B K-window
    const int scolS = acolb ^ swz(arow);
    const char* Ab = (const char*)A + ((long)(m0 + arow) * K) * 2 + scolS;
    const char* Bb = (const char*)Bw + ((long)(n0 + arow) * K) * 2 + scolS;

    for (int k0 = 0; k0 < K; k0 += 64) {
        #pragma unroll
        for (int i = 0; i < 4; ++i)
            gload_lds16(Ab + ((long)i * 32 * K + k0) * 2, (char*)As + i * 4096 + tid * 16);
        #pragma unroll
        for (int i = 0; i < NFRAG; ++i)
            gload_lds16(Bb + ((long)i * 32 * K + k0) * 2, (char*)Bs + i * 4096 + tid * 16);
        __syncthreads();
        #pragma unroll
        for (int ks = 0; ks < 2; ++ks) {
            short8 af[4], bf[NFRAG];
            #pragma unroll
            for (int fm = 0; fm < 4; ++fm) {
                const int row = wm * 64 + fm * 16 + lo;
                af[fm] = *reinterpret_cast<const short8*>(
                    (const char*)As + row * 128 + ((ks * 64 + hi * 16) ^ swz(row)));
            }
            #pragma unroll
            for (int fn = 0; fn < NFRAG; ++fn) {
                const int row = wn * (BN / 2) + fn * 16 + lo;
                bf[fn] = *reinterpret_cast<const short8*>(
                    (const char*)Bs + row * 128 + ((ks * 64 + hi * 16) ^ swz(row)));
            }
            #pragma unroll
            for (int fm = 0; fm < 4; ++fm)
                #pragma unroll
                for (int fn = 0; fn < NFRAG; ++fn)
                    acc[fm][fn] = __builtin_amdgcn_mfma_f32_16x16x32_bf16(
                        af[fm], bf[fn], acc[fm][fn], 0, 0, 0);
        }
        __syncthreads();
    }

    #pragma unroll
    for (int fm = 0; fm < 4; ++fm)
        #pragma unroll
        for (int fn = 0; fn < NFRAG; ++fn) {
            const int n = n0 + wn * (BN / 2) + fn * 16 + lo;
            const int mB = m0 + wm * 64 + fm * 16 + hi * 4;
            for (int r = 0; r < 4; ++r) epi(mB + r, n, acc[fm][fn][r]);
        }
}

// qkv GEMM block body (logical block index 0..767)
static __device__ __forceinline__
void qkv_body(short* smem, int qb,
              const short* xq, const short* xk, const short* xv,
              const short* wq, const short* wk, const short* wv,
              const float* bq, const float* bk, const float* bv,
              short* Qb, short* Kb, short* Vt) {
    const int which = qb >> 8;
    const int bid   = qb & 255;
    const int m0 = (bid >> 3) << 7;
    const int n0 = (bid & 7) << 7;
    const short* A    = which == 0 ? xq : which == 1 ? xk : xv;
    const short* W    = which == 0 ? wq : which == 1 ? wk : wv;
    const float* bias = which == 0 ? bq : which == 1 ? bk : bv;
    short* C          = which == 0 ? Qb : which == 1 ? Kb : Vt;
    const float scale = which == 0 ? QSCALE : 1.0f;
    gemm_core<128>(smem, A, W, HDIM, m0, n0, [&](int m, int n, float v) {
        v = (v + bias[n]) * scale;
        const int b = m >> 11, s = m & (SEQ - 1);
        const int h = n >> 6, d = n & 63;
        long idx;
        if (which != 2) idx = (((long)(b * NHEADS + h)) * SEQ + s) * HEADD + d;
        else            idx = (((long)(b * NHEADS + h)) * HEADD + d) * SEQ + s;
        C[idx] = f2bf(v);
    });
}

// standalone qkv projection (serial fallback): grid = 768
__global__ __launch_bounds__(256, 3)
void qkv_gemm(const short* xq, const short* xk, const short* xv,
              const short* wq, const short* wk, const short* wv,
              const float* bq, const float* bk, const float* bv,
              short* Qb, short* Kb, short* Vt) {
    __shared__ short smem[16640];
    qkv_body(smem, blockIdx.x, xq, xk, xv, wq, wk, wv, bq, bk, bv, Qb, Kb, Vt);
}

// fused qkv + fuse_rel: grid = 1280; blockIdx%5 in {0,1,2} -> qkv, {3,4} -> rel.
// Interleaved so each CU co-schedules compute-bound and memory-bound blocks.
__global__ __launch_bounds__(256, 3)
void qkv_rel_kernel(const short* xq, const short* xk, const short* xv,
                    const short* wq, const short* wk, const short* wv,
                    const float* bq, const float* bk, const float* bv,
                    short* Qb, short* Kb, short* Vt,
                    const float* rel, const void* mask, const int* flag, short* rT) {
    __shared__ short smem[16640];
    const int r = blockIdx.x % 5;
    const int g = blockIdx.x / 5;
    if (r < 3) {
        qkv_body(smem, g * 3 + r, xq, xk, xv, wq, wk, wv, bq, bk, bv, Qb, Kb, Vt);
    } else {
        fuse_rel_body(smem, g * 2 + (r - 3), rel, mask, flag[0], rT);
    }
}

// final output projection: f32 out [M,N]; 128x64 tiles -> 512 blocks (2/CU)
__global__ __launch_bounds__(256, 2)
void out_gemm(const short* A, const short* W, const float* bias, float* Cout) {
    __shared__ short smem[(128 + 64) * 64];
    const int bid = blockIdx.x;
    const int m0 = (bid >> 4) << 7;
    const int n0 = (bid & 15) << 6;
    gemm_core<64>(smem, A, W, HDIM, m0, n0, [&](int m, int n, float v) {
        Cout[(long)m * HDIM + n] = v + bias[n];
    });
}

// ---------------- flash attention (32x32 swapped, P in-register) ----------------
// grid 1024 (XCD-chunked); QBLK=64: 4 waves = 2 q-panels (32 q) x 2 kv-halves.
// Counted-vmcnt double-buffer (R14-proven): stage(next) -> vmcnt(4) -> barrier
// -> compute -> barrier.
__global__ __launch_bounds__(256, 4)
void attn_fwd(const short* __restrict__ Qb, const short* __restrict__ Kb,
              const short* __restrict__ Vtb, const short* __restrict__ rT,
              short* __restrict__ Ob) {
    __shared__ short Ks[2][64 * 64];
    __shared__ short Vs[2][64 * 64];
    const int tid  = threadIdx.x;
    const int lane = tid & 63;
    const int wv   = tid >> 6;
    const int qp   = wv & 1;            // q panel (32 q)
    const int t    = wv >> 1;           // kv half within the 64-tile
    const int l31  = lane & 31, hi2 = lane >> 5;
    // XCD-chunked swizzle: 1024 blocks, 8 XCDs, 128 contiguous wgs each
    const int wg = ((blockIdx.x & 7) << 7) + (blockIdx.x >> 3);
    const int qt = wg & 31, h = (wg >> 5) & 15, b = wg >> 9;
    const int bh = b * NHEADS + h;
    const int q0 = qt * 64 + qp * 32 + l31;   // this lane's q row

    // Q as B-fragments: qf[s] = Q[q0][s*16 + hi2*8 .. +7]
    short8 qf[4];
    {
        const short* qp_ = Qb + ((long)bh * SEQ + q0) * HEADD + hi2 * 8;
        #pragma unroll
        for (int s = 0; s < 4; ++s)
            qf[s] = *reinterpret_cast<const short8*>(qp_ + s * 16);
    }

    float lsum = 0.0f;
    f32x16 oacc0 = {}, oacc1 = {};

    // K/V staging (pre-swizzled global source -> linear LDS dest); all 4 waves stage
    const int srow  = tid >> 3;
    const int scolb = (tid & 7) * 16;
    const int scolK = scolb ^ swz(srow);
    const char* KbB = (const char*)Kb + ((long)bh * SEQ + srow) * 128 + scolK;
    const char* VbB = (const char*)Vtb + ((long)bh * HEADD + srow) * ((long)SEQ * 2) + scolK;

    auto stage = [&](int buf, int kt) {
        #pragma unroll
        for (int i = 0; i < 2; ++i) {
            gload_lds16(KbB + ((long)kt * 64 + i * 32) * 128,
                        (char*)&Ks[buf][0] + i * 4096 + tid * 16);
            gload_lds16(VbB + (long)i * 32 * (SEQ * 2) + (long)kt * 128,
                        (char*)&Vs[buf][0] + i * 4096 + tid * 16);
        }
    };

    // bias C-init prefetch (bf16x4 planes); wave covers planes t*8 + {0..7}
    ushort4v rbuf[4];
    auto loadRel = [&](int kt) {
        #pragma unroll
        for (int g = 0; g < 4; ++g) {
            const int p4 = kt * 16 + t * 8 + 2 * g + hi2;
            rbuf[g] = *reinterpret_cast<const ushort4v*>(
                rT + (((long)(b * 512 + p4)) * 2048 + q0) * 4);
        }
    };

    stage(0, 0);      // 4 VMEM
    loadRel(0);       // 4 VMEM

    const int rsw = swz(l31);
    const int NT = SEQ / 64;

    for (int kt = 0; kt < NT; ++kt) {
        const int cb = kt & 1;
        const bool hasNext = (kt < NT - 1);
        if (hasNext) stage(cb ^ 1, kt + 1);
        // FIFO: [stage(kt) 4 | rel(kt) 4 | stage(kt+1) 4?]; complete stage(kt)+rel(kt).
        if (hasNext) asm volatile("s_waitcnt vmcnt(4)" ::: "memory");
        else         asm volatile("s_waitcnt vmcnt(0)" ::: "memory");
        __builtin_amdgcn_s_barrier();          // cross-wave: buf[cb] fully staged
        asm volatile("" ::: "memory");

        // C-init from prefetched bias (sc[4g+j] -> kv-local row 8g+4hi2+j)
        f32x16 sc;
        #pragma unroll
        for (int g = 0; g < 4; ++g)
            #pragma unroll
            for (int j = 0; j < 4; ++j)
                sc[4 * g + j] = bfbits2f(rbuf[g][j]);
        if (hasNext) loadRel(kt + 1);

        // QK^T (swapped): this wave's kv half; D row=kv-local, col=q
        const char* kr = (const char*)&Ks[cb][0] + (t * 32 + l31) * 128;
        __builtin_amdgcn_s_setprio(1);
        #pragma unroll
        for (int s = 0; s < 4; ++s) {
            short8 kf = *reinterpret_cast<const short8*>(kr + ((s * 32 + hi2 * 16) ^ rsw));
            sc = __builtin_amdgcn_mfma_f32_32x32x16_bf16(kf, qf[s], sc, 0, 0, 0);
        }
        __builtin_amdgcn_s_setprio(0);

        // fixed-shift softmax: p = 2^sc; pack + permlane into PV A-fragments.
        // permlane32_swap(lowkv, highkv): ret[0] = lo-kv word, ret[1] = hi-kv word
        int X[8];
        #pragma unroll
        for (int i2 = 0; i2 < 8; ++i2) {
            const float p0 = __builtin_amdgcn_exp2f(sc[2 * i2]);
            const float p1 = __builtin_amdgcn_exp2f(sc[2 * i2 + 1]);
            lsum += p0 + p1;
            X[i2] = cvt_pk_bf16(p0, p1);
        }
        int pa[2][4];
        #pragma unroll
        for (int u = 0; u < 2; ++u) {
            auto r0 = __builtin_amdgcn_permlane32_swap(X[4 * u + 0], X[4 * u + 2], false, false);
            auto r1 = __builtin_amdgcn_permlane32_swap(X[4 * u + 1], X[4 * u + 3], false, false);
            pa[u][0] = (int)r0[0];
            pa[u][1] = (int)r1[0];
            pa[u][2] = (int)r0[1];
            pa[u][3] = (int)r1[1];
        }

        // PV: oacc[dt] += P(A) x V(B); wave's kv windows s = 2t+u
        const char* vls = (const char*)&Vs[cb][0];
        __builtin_amdgcn_s_setprio(1);
        #pragma unroll
        for (int dt = 0; dt < 2; ++dt) {
            const char* vr = vls + (dt * 32 + l31) * 128;
            #pragma unroll
            for (int u = 0; u < 2; ++u) {
                const int s = 2 * t + u;
                short8 vf = *reinterpret_cast<const short8*>(vr + ((s * 32 + hi2 * 16) ^ rsw));
                int4v pw = { pa[u][0], pa[u][1], pa[u][2], pa[u][3] };
                if (dt == 0)
                    oacc0 = __builtin_amdgcn_mfma_f32_32x32x16_bf16(
                        __builtin_bit_cast(short8, pw), vf, oacc0, 0, 0, 0);
                else
                    oacc1 = __builtin_amdgcn_mfma_f32_32x32x16_bf16(
                        __builtin_bit_cast(short8, pw), vf, oacc1, 0, 0, 0);
            }
        }
        __builtin_amdgcn_s_setprio(0);

        asm volatile("" ::: "memory");
        __builtin_amdgcn_s_barrier();          // all reads of buf[cb] done before overwrite
    }

    // per-wave row sum over its kv half (halves of the wave hold complementary kv rows)
    lsum += __shfl_xor(lsum, 32, 64);

    // combine the two kv-half waves of each q-panel via LDS (Ks/Vs are dead now)
    float* cmbO = (float*)&Ks[0][0];          // [qp][32 q][64 d] f32 = 16 KB
    float* cmbL = (float*)&Vs[0][0];          // [qp][32 q] f32
    if (t == 1) {
        #pragma unroll
        for (int r = 0; r < 16; ++r) {
            const int qloc = (r & 3) + 8 * (r >> 2) + 4 * hi2;
            cmbO[(qp * 32 + qloc) * 64 + l31]      = oacc0[r];
            cmbO[(qp * 32 + qloc) * 64 + 32 + l31] = oacc1[r];
        }
        if (hi2 == 0) cmbL[qp * 32 + l31] = lsum;
    }
    __syncthreads();
    if (t == 0) {
        const float ltot = lsum + cmbL[qp * 32 + l31];
        const float inv  = ltot > 0.0f ? 1.0f / ltot : 0.0f;
        #pragma unroll
        for (int r = 0; r < 16; ++r) {
            const int qloc = (r & 3) + 8 * (r >> 2) + 4 * hi2;
            const float invr = __shfl(inv, qloc, 64);
            const int qg = qt * 64 + qp * 32 + qloc;
            const long obase = ((long)b * SEQ + qg) * HDIM + h * 64 + l31;
            const float o0 = oacc0[r] + cmbO[(qp * 32 + qloc) * 64 + l31];
            const float o1 = oacc1[r] + cmbO[(qp * 32 + qloc) * 64 + 32 + l31];
            Ob[obase]      = f2bf(o0 * invr);
            Ob[obase + 32] = f2bf(o1 * invr);
        }
    }
}

// ---------------- host launch ----------------
extern "C" void kernel_launch(void* const* d_in, const int* in_sizes, int n_in,
                              void* d_out, int out_size, void* d_ws, size_t ws_size,
                              hipStream_t stream) {
    const float* q    = (const float*)d_in[0];
    const float* k    = (const float*)d_in[1];
    const float* v    = (const float*)d_in[2];
    const void*  mask = d_in[3];
    const float* rel  = (const float*)d_in[4];
    const float* Wq   = (const float*)d_in[5];
    const float* bq   = (const float*)d_in[6];
    const float* Wk   = (const float*)d_in[7];
    const float* bk   = (const float*)d_in[8];
    const float* Wv   = (const float*)d_in[9];
    const float* bv   = (const float*)d_in[10];
    const float* Wo   = (const float*)d_in[11];
    const float* bo   = (const float*)d_in[12];
    (void)in_sizes; (void)n_in; (void)out_size;

    char* ws = (char*)d_ws;
    size_t off = 0;
    auto alloc = [&](size_t bytes) {
        char* p = ws + off;
        off += (bytes + 255) & ~(size_t)255;
        return p;
    };
    const size_t xBytes  = (size_t)MROWS * HDIM * 2;        // 8 MB bf16
    const size_t wBytes  = (size_t)HDIM * HDIM * 2;         // 2 MB bf16
    const size_t poolBytes = 3 * xBytes + 3 * wBytes;       // 30 MB
    const size_t rtBytes = (size_t)BATCH * 2048 * 2048 * 2; // 16 MB bf16

    // persistent region
    short* Qb  = (short*)alloc(xBytes);
    short* Kb  = (short*)alloc(xBytes);
    short* Vt  = (short*)alloc(xBytes);
    short* wob = (short*)alloc(wBytes);
    int*   flag = (int*)alloc(256);
    char*  pool = (char*)alloc(poolBytes);     // xq..wvb (phase 1)
    short* Ab  = (short*)alloc(xBytes);

    short* xq  = (short*)(pool);
    short* xk  = (short*)(pool + xBytes);
    short* xv  = (short*)(pool + 2 * xBytes);
    short* wqb = (short*)(pool + 3 * xBytes);
    short* wkb = (short*)(pool + 3 * xBytes + wBytes);
    short* wvb = (short*)(pool + 3 * xBytes + 2 * wBytes);

    // rT: separate allocation if workspace allows (enables qkv+rel fusion);
    // else overlay on pool (serial schedule, R14-proven).
    const bool fused = (off + rtBytes + 256) <= ws_size;
    short* rT = fused ? (short*)alloc(rtBytes) : (short*)pool;

    const int n4x = MROWS * HDIM / 4, n4w = HDIM * HDIM / 4;
    cvt_all_kernel<<<2048, 256, 0, stream>>>(q, k, v, Wq, Wk, Wv, Wo,
                                             xq, xk, xv, wqb, wkb, wvb, wob, n4x, n4w);
    detect_mask_kernel<<<1, 256, 0, stream>>>((const unsigned int*)mask, flag);

    if (fused) {
        qkv_rel_kernel<<<1280, 256, 0, stream>>>(xq, xk, xv, wqb, wkb, wvb,
                                                 bq, bk, bv, Qb, Kb, Vt,
                                                 rel, mask, flag, rT);
    } else {
        qkv_gemm<<<768, 256, 0, stream>>>(xq, xk, xv, wqb, wkb, wvb,
                                          bq, bk, bv, Qb, Kb, Vt);
        fuse_rel_kernel<<<512, 256, 0, stream>>>(rel, mask, flag, rT);
    }

    attn_fwd<<<1024, 256, 0, stream>>>(Qb, Kb, Vt, rT, Ab);

    out_gemm<<<512, 256, 0, stream>>>(Ab, wob, bo, (float*)d_out);
}

// Round 17
// 155.401 us; speedup vs baseline: 1.0732x; 1.0732x over previous
//
#include <hip/hip_runtime.h>
#include <hip/hip_bf16.h>

// Problem constants
constexpr int BATCH = 2, SEQ = 2048, HDIM = 1024, NHEADS = 16, HEADD = 64;
constexpr int MROWS = BATCH * SEQ;            // 4096
// fold attention scale and exp->exp2 conversion: c = 0.125 / ln(2)
constexpr float QSCALE = 0.18033688011112042f;

typedef short short8  __attribute__((ext_vector_type(8)));
typedef float f32x4   __attribute__((ext_vector_type(4)));
typedef float f32x16  __attribute__((ext_vector_type(16)));
typedef int   int4v   __attribute__((ext_vector_type(4)));
typedef unsigned short ushort4v __attribute__((ext_vector_type(4)));

static __device__ __forceinline__ short f2bf(float f) {
    __hip_bfloat16 h = __float2bfloat16(f);
    return *reinterpret_cast<short*>(&h);
}

static __device__ __forceinline__ int cvt_pk_bf16(float a, float b) {
    int r;
    asm("v_cvt_pk_bf16_f32 %0, %1, %2" : "=v"(r) : "v"(a), "v"(b));
    return r;
}

static __device__ __forceinline__ float bfbits2f(unsigned short u) {
    return __builtin_bit_cast(float, (unsigned int)u << 16);
}

static __device__ __forceinline__ void gload_lds16(const void* g, void* l) {
    __builtin_amdgcn_global_load_lds(
        (const __attribute__((address_space(1))) unsigned int*)g,
        (__attribute__((address_space(3))) unsigned int*)l, 16, 0, 0);
}

// swizzle slot function: row-periodic mod 32, involution on 16B slots
static __device__ __forceinline__ int swz(int row) {
    return (((row & 7) ^ ((row >> 3) & 3))) << 4;
}

// ---------------- conversions: f32 -> bf16, all 7 tensors, one launch ----------------
__global__ void cvt_all_kernel(const float* __restrict__ q, const float* __restrict__ k,
                               const float* __restrict__ v, const float* __restrict__ w0,
                               const float* __restrict__ w1, const float* __restrict__ w2,
                               const float* __restrict__ w3,
                               short* __restrict__ xq, short* __restrict__ xk,
                               short* __restrict__ xv, short* __restrict__ o0,
                               short* __restrict__ o1, short* __restrict__ o2,
                               short* __restrict__ o3, int n4x, int n4w) {
    int i = blockIdx.x * blockDim.x + threadIdx.x;
    const int stride = gridDim.x * blockDim.x;
    const int total = 3 * n4x + 4 * n4w;
    for (; i < total; i += stride) {
        const float* in; short* out; int j = i;
        if (j < 3 * n4x) {
            if (j >= 2 * n4x)      { in = v; out = xv; j -= 2 * n4x; }
            else if (j >= n4x)     { in = k; out = xk; j -= n4x; }
            else                   { in = q; out = xq; }
        } else {
            j -= 3 * n4x;
            if (j >= 3 * n4w)      { in = w3; out = o3; j -= 3 * n4w; }
            else if (j >= 2 * n4w) { in = w2; out = o2; j -= 2 * n4w; }
            else if (j >= n4w)     { in = w1; out = o1; j -= n4w; }
            else                   { in = w0; out = o0; }
        }
        const float4 val = reinterpret_cast<const float4*>(in)[j];
        short4 o;
        o.x = f2bf(val.x); o.y = f2bf(val.y); o.z = f2bf(val.z); o.w = f2bf(val.w);
        reinterpret_cast<short4*>(out)[j] = o;
    }
}

// ---------------- mask dtype probe ----------------
__global__ void detect_mask_kernel(const unsigned int* __restrict__ m, int* flag) {
    const int tid = threadIdx.x;
    int gt1 = 0, isf = 0;
    for (int i = 0; i < 4; ++i) {
        unsigned int wv = m[tid + 256 * i];
        if (wv > 1u) gt1 = 1;
        if (wv == 0x3F800000u) isf = 1;
    }
    __shared__ int s_gt1, s_isf;
    if (tid == 0) { s_gt1 = 0; s_isf = 0; }
    __syncthreads();
    if (gt1) atomicOr(&s_gt1, 1);
    if (isf) atomicOr(&s_isf, 1);
    __syncthreads();
    if (tid == 0) flag[0] = s_gt1 ? (s_isf ? 2 : 1) : 0;
}

// ---------------- fuse mask + rel -> rT (LDS tile transpose, coalesced) ----------------
// rT short4-index [(b*512 + kv/4)*2048 + q], component j = kv%4:
//   rT[...][j] = mask[b][q][kv] ? bf16(rel[b][q][kv] * QSCALE) : bf16(-1e30f)
__global__ __launch_bounds__(256)
void fuse_rel_kernel(const float* __restrict__ rel, const void* __restrict__ mask,
                     const int* __restrict__ flag, short* __restrict__ rT) {
    constexpr int QT = 64, KT = 256;
    constexpr int STRIDE = KT + 4;            // bf16 elements; +8B pad
    __shared__ short tile[QT * STRIDE];       // 33,280 B
    const int f   = flag[0];
    const int bid = blockIdx.x;
    const int b   = bid >> 8;                 // 256 tiles per batch
    const int t8  = (bid >> 5) & 7;           // kv-tile 0..7
    const int t32 = bid & 31;                 // q-tile 0..31
    const int q0  = t32 * QT;
    const int kv0 = t8 * KT;
    const int tid = threadIdx.x;

    // phase 1: coalesced read -> masked bf16 -> LDS
    const int c4 = tid & 63;                  // float4 col in row (0..63)
    const int r4 = tid >> 6;                  // row sub-index (0..3)
    #pragma unroll 4
    for (int it = 0; it < 16; ++it) {
        const int row = it * 4 + r4;
        const long src = ((long)(b * 2048 + q0 + row)) * 2048 + kv0 + c4 * 4;
        const float4 v = *reinterpret_cast<const float4*>(rel + src);
        bool mk[4];
        if (f == 1) {
            const unsigned int mw =
                *reinterpret_cast<const unsigned int*>((const unsigned char*)mask + src);
            mk[0] = (mw & 0xffu) != 0;       mk[1] = (mw & 0xff00u) != 0;
            mk[2] = (mw & 0xff0000u) != 0;   mk[3] = (mw & 0xff000000u) != 0;
        } else if (f == 0) {
            const int4 mi = *reinterpret_cast<const int4*>((const int*)mask + src);
            mk[0] = mi.x != 0; mk[1] = mi.y != 0; mk[2] = mi.z != 0; mk[3] = mi.w != 0;
        } else {
            const float4 mf = *reinterpret_cast<const float4*>((const float*)mask + src);
            mk[0] = mf.x != 0.0f; mk[1] = mf.y != 0.0f;
            mk[2] = mf.z != 0.0f; mk[3] = mf.w != 0.0f;
        }
        short4 o;
        o.x = f2bf(mk[0] ? v.x * QSCALE : -1e30f);
        o.y = f2bf(mk[1] ? v.y * QSCALE : -1e30f);
        o.z = f2bf(mk[2] ? v.z * QSCALE : -1e30f);
        o.w = f2bf(mk[3] ? v.w * QSCALE : -1e30f);
        *reinterpret_cast<short4*>(&tile[row * STRIDE + c4 * 4]) = o;
    }
    __syncthreads();

    // phase 2: transposed coalesced write of 64 planes (p = kv>>2)
    const int qq  = tid & 63;                 // q within tile
    const int p4r = tid >> 6;                 // plane sub-index 0..3
    #pragma unroll 4
    for (int it = 0; it < 16; ++it) {
        const int pl = it * 4 + p4r;          // local plane 0..63
        const short4 o = *reinterpret_cast<const short4*>(&tile[qq * STRIDE + pl * 4]);
        *reinterpret_cast<short4*>(
            rT + (((long)(b * 512 + (kv0 >> 2) + pl)) * 2048 + q0 + qq) * 4) = o;
    }
}

// ===== GEMM core (128xBN tile, BK=64, single-buffer 2-phase, XOR-swizzled LDS) =====
template<int BN, typename EPI>
static __device__ __forceinline__
void gemm_core(const short* A, const short* Bw, int K, int m0, int n0, EPI epi) {
    constexpr int NFRAG = BN / 32;        // n fragments per wave
    __shared__ short As[128 * 64];
    __shared__ short Bs[BN * 64];
    const int tid  = threadIdx.x;
    const int lane = tid & 63;
    const int w    = tid >> 6;
    const int lo   = lane & 15, hi = lane >> 4;
    const int wm   = w >> 1, wn = w & 1;

    f32x4 acc[4][NFRAG] = {};

    // staging: pre-swizzled global source column -> linear LDS dest
    const int arow  = tid >> 3;                 // 0..31
    const int acolb = (tid & 7) * 16;           // byte col in 128B K-window
    const int scolS = acolb ^ swz(arow);
    const char* Ab = (const char*)A + ((long)(m0 + arow) * K) * 2 + scolS;
    const char* Bb = (const char*)Bw + ((long)(n0 + arow) * K) * 2 + scolS;

    for (int k0 = 0; k0 < K; k0 += 64) {
        #pragma unroll
        for (int i = 0; i < 4; ++i)
            gload_lds16(Ab + ((long)i * 32 * K + k0) * 2, (char*)As + i * 4096 + tid * 16);
        #pragma unroll
        for (int i = 0; i < NFRAG; ++i)
            gload_lds16(Bb + ((long)i * 32 * K + k0) * 2, (char*)Bs + i * 4096 + tid * 16);
        __syncthreads();
        #pragma unroll
        for (int ks = 0; ks < 2; ++ks) {
            short8 af[4], bf[NFRAG];
            #pragma unroll
            for (int fm = 0; fm < 4; ++fm) {
                const int row = wm * 64 + fm * 16 + lo;
                af[fm] = *reinterpret_cast<const short8*>(
                    (const char*)As + row * 128 + ((ks * 64 + hi * 16) ^ swz(row)));
            }
            #pragma unroll
            for (int fn = 0; fn < NFRAG; ++fn) {
                const int row = wn * (BN / 2) + fn * 16 + lo;
                bf[fn] = *reinterpret_cast<const short8*>(
                    (const char*)Bs + row * 128 + ((ks * 64 + hi * 16) ^ swz(row)));
            }
            #pragma unroll
            for (int fm = 0; fm < 4; ++fm)
                #pragma unroll
                for (int fn = 0; fn < NFRAG; ++fn)
                    acc[fm][fn] = __builtin_amdgcn_mfma_f32_16x16x32_bf16(
                        af[fm], bf[fn], acc[fm][fn], 0, 0, 0);
        }
        __syncthreads();
    }

    #pragma unroll
    for (int fm = 0; fm < 4; ++fm)
        #pragma unroll
        for (int fn = 0; fn < NFRAG; ++fn) {
            const int n = n0 + wn * (BN / 2) + fn * 16 + lo;
            const int mB = m0 + wm * 64 + fm * 16 + hi * 4;
            for (int r = 0; r < 4; ++r) epi(mB + r, n, acc[fm][fn][r]);
        }
}

// merged Q/K/V projection: grid = 3*256 blocks; which = blockIdx.x>>8
__global__ __launch_bounds__(256, 3)
void qkv_gemm(const short* xq, const short* xk, const short* xv,
              const short* wq, const short* wk, const short* wv,
              const float* bq, const float* bk, const float* bv,
              short* Qb, short* Kb, short* Vt) {
    const int which = blockIdx.x >> 8;
    const int bid   = blockIdx.x & 255;
    const int m0 = (bid >> 3) << 7;
    const int n0 = (bid & 7) << 7;
    const short* A    = which == 0 ? xq : which == 1 ? xk : xv;
    const short* W    = which == 0 ? wq : which == 1 ? wk : wv;
    const float* bias = which == 0 ? bq : which == 1 ? bk : bv;
    short* C          = which == 0 ? Qb : which == 1 ? Kb : Vt;
    const float scale = which == 0 ? QSCALE : 1.0f;
    gemm_core<128>(A, W, HDIM, m0, n0, [&](int m, int n, float v) {
        v = (v + bias[n]) * scale;
        const int b = m >> 11, s = m & (SEQ - 1);
        const int h = n >> 6, d = n & 63;
        long idx;
        if (which != 2) idx = (((long)(b * NHEADS + h)) * SEQ + s) * HEADD + d;
        else            idx = (((long)(b * NHEADS + h)) * HEADD + d) * SEQ + s;
        C[idx] = f2bf(v);
    });
}

// final output projection: f32 out [M,N]; 128x64 tiles -> 512 blocks (2/CU)
__global__ __launch_bounds__(256, 2)
void out_gemm(const short* A, const short* W, const float* bias, float* Cout) {
    const int bid = blockIdx.x;
    const int m0 = (bid >> 4) << 7;
    const int n0 = (bid & 15) << 6;
    gemm_core<64>(A, W, HDIM, m0, n0, [&](int m, int n, float v) {
        Cout[(long)m * HDIM + n] = v + bias[n];
    });
}

// ---------------- flash attention (32x32 swapped, P in-register) ----------------
// grid 1024 (XCD-chunked); QBLK=64: 4 waves = 2 q-panels (32 q) x 2 kv-halves.
// Counted-vmcnt double-buffer (proven): stage(next) -> vmcnt(4) -> barrier
// -> compute -> barrier.
__global__ __launch_bounds__(256, 4)
void attn_fwd(const short* __restrict__ Qb, const short* __restrict__ Kb,
              const short* __restrict__ Vtb, const short* __restrict__ rT,
              short* __restrict__ Ob) {
    __shared__ short Ks[2][64 * 64];
    __shared__ short Vs[2][64 * 64];
    const int tid  = threadIdx.x;
    const int lane = tid & 63;
    const int wv   = tid >> 6;
    const int qp   = wv & 1;            // q panel (32 q)
    const int t    = wv >> 1;           // kv half within the 64-tile
    const int l31  = lane & 31, hi2 = lane >> 5;
    // XCD-chunked swizzle: 1024 blocks, 8 XCDs, 128 contiguous wgs each
    const int wg = ((blockIdx.x & 7) << 7) + (blockIdx.x >> 3);
    const int qt = wg & 31, h = (wg >> 5) & 15, b = wg >> 9;
    const int bh = b * NHEADS + h;
    const int q0 = qt * 64 + qp * 32 + l31;   // this lane's q row

    // Q as B-fragments: qf[s] = Q[q0][s*16 + hi2*8 .. +7]
    short8 qf[4];
    {
        const short* qp_ = Qb + ((long)bh * SEQ + q0) * HEADD + hi2 * 8;
        #pragma unroll
        for (int s = 0; s < 4; ++s)
            qf[s] = *reinterpret_cast<const short8*>(qp_ + s * 16);
    }

    float lsum = 0.0f;
    f32x16 oacc0 = {}, oacc1 = {};

    // K/V staging (pre-swizzled global source -> linear LDS dest); all 4 waves stage
    const int srow  = tid >> 3;
    const int scolb = (tid & 7) * 16;
    const int scolK = scolb ^ swz(srow);
    const char* KbB = (const char*)Kb + ((long)bh * SEQ + srow) * 128 + scolK;
    const char* VbB = (const char*)Vtb + ((long)bh * HEADD + srow) * ((long)SEQ * 2) + scolK;

    auto stage = [&](int buf, int kt) {
        #pragma unroll
        for (int i = 0; i < 2; ++i) {
            gload_lds16(KbB + ((long)kt * 64 + i * 32) * 128,
                        (char*)&Ks[buf][0] + i * 4096 + tid * 16);
            gload_lds16(VbB + (long)i * 32 * (SEQ * 2) + (long)kt * 128,
                        (char*)&Vs[buf][0] + i * 4096 + tid * 16);
        }
    };

    // bias C-init prefetch (bf16x4 planes); wave covers planes t*8 + {0..7}
    ushort4v rbuf[4];
    auto loadRel = [&](int kt) {
        #pragma unroll
        for (int g = 0; g < 4; ++g) {
            const int p4 = kt * 16 + t * 8 + 2 * g + hi2;
            rbuf[g] = *reinterpret_cast<const ushort4v*>(
                rT + (((long)(b * 512 + p4)) * 2048 + q0) * 4);
        }
    };

    stage(0, 0);      // 4 VMEM
    loadRel(0);       // 4 VMEM

    const int rsw = swz(l31);
    const int NT = SEQ / 64;

    for (int kt = 0; kt < NT; ++kt) {
        const int cb = kt & 1;
        const bool hasNext = (kt < NT - 1);
        if (hasNext) stage(cb ^ 1, kt + 1);
        // FIFO: [stage(kt) 4 | rel(kt) 4 | stage(kt+1) 4?]; complete stage(kt)+rel(kt).
        if (hasNext) asm volatile("s_waitcnt vmcnt(4)" ::: "memory");
        else         asm volatile("s_waitcnt vmcnt(0)" ::: "memory");
        __builtin_amdgcn_s_barrier();          // cross-wave: buf[cb] fully staged
        asm volatile("" ::: "memory");

        // C-init from prefetched bias (sc[4g+j] -> kv-local row 8g+4hi2+j)
        f32x16 sc;
        #pragma unroll
        for (int g = 0; g < 4; ++g)
            #pragma unroll
            for (int j = 0; j < 4; ++j)
                sc[4 * g + j] = bfbits2f(rbuf[g][j]);
        if (hasNext) loadRel(kt + 1);

        // QK^T (swapped): this wave's kv half; D row=kv-local, col=q
        const char* kr = (const char*)&Ks[cb][0] + (t * 32 + l31) * 128;
        __builtin_amdgcn_s_setprio(1);
        #pragma unroll
        for (int s = 0; s < 4; ++s) {
            short8 kf = *reinterpret_cast<const short8*>(kr + ((s * 32 + hi2 * 16) ^ rsw));
            sc = __builtin_amdgcn_mfma_f32_32x32x16_bf16(kf, qf[s], sc, 0, 0, 0);
        }
        __builtin_amdgcn_s_setprio(0);

        // fixed-shift softmax: p = 2^sc; pack + permlane into PV A-fragments.
        // permlane32_swap(lowkv, highkv): ret[0] = lo-kv word, ret[1] = hi-kv word
        int X[8];
        #pragma unroll
        for (int i2 = 0; i2 < 8; ++i2) {
            const float p0 = __builtin_amdgcn_exp2f(sc[2 * i2]);
            const float p1 = __builtin_amdgcn_exp2f(sc[2 * i2 + 1]);
            lsum += p0 + p1;
            X[i2] = cvt_pk_bf16(p0, p1);
        }
        int pa[2][4];
        #pragma unroll
        for (int u = 0; u < 2; ++u) {
            auto r0 = __builtin_amdgcn_permlane32_swap(X[4 * u + 0], X[4 * u + 2], false, false);
            auto r1 = __builtin_amdgcn_permlane32_swap(X[4 * u + 1], X[4 * u + 3], false, false);
            pa[u][0] = (int)r0[0];
            pa[u][1] = (int)r1[0];
            pa[u][2] = (int)r0[1];
            pa[u][3] = (int)r1[1];
        }

        // PV: oacc[dt] += P(A) x V(B); wave's kv windows s = 2t+u
        const char* vls = (const char*)&Vs[cb][0];
        __builtin_amdgcn_s_setprio(1);
        #pragma unroll
        for (int dt = 0; dt < 2; ++dt) {
            const char* vr = vls + (dt * 32 + l31) * 128;
            #pragma unroll
            for (int u = 0; u < 2; ++u) {
                const int s = 2 * t + u;
                short8 vf = *reinterpret_cast<const short8*>(vr + ((s * 32 + hi2 * 16) ^ rsw));
                int4v pw = { pa[u][0], pa[u][1], pa[u][2], pa[u][3] };
                if (dt == 0)
                    oacc0 = __builtin_amdgcn_mfma_f32_32x32x16_bf16(
                        __builtin_bit_cast(short8, pw), vf, oacc0, 0, 0, 0);
                else
                    oacc1 = __builtin_amdgcn_mfma_f32_32x32x16_bf16(
                        __builtin_bit_cast(short8, pw), vf, oacc1, 0, 0, 0);
            }
        }
        __builtin_amdgcn_s_setprio(0);

        asm volatile("" ::: "memory");
        __builtin_amdgcn_s_barrier();          // all reads of buf[cb] done before overwrite
    }

    // per-wave row sum over its kv half (halves of the wave hold complementary kv rows)
    lsum += __shfl_xor(lsum, 32, 64);

    // combine the two kv-half waves of each q-panel via LDS (Ks/Vs are dead now)
    float* cmbO = (float*)&Ks[0][0];          // [qp][32 q][64 d] f32 = 16 KB
    float* cmbL = (float*)&Vs[0][0];          // [qp][32 q] f32
    if (t == 1) {
        #pragma unroll
        for (int r = 0; r < 16; ++r) {
            const int qloc = (r & 3) + 8 * (r >> 2) + 4 * hi2;
            cmbO[(qp * 32 + qloc) * 64 + l31]      = oacc0[r];
            cmbO[(qp * 32 + qloc) * 64 + 32 + l31] = oacc1[r];
        }
        if (hi2 == 0) cmbL[qp * 32 + l31] = lsum;
    }
    __syncthreads();
    if (t == 0) {
        const float ltot = lsum + cmbL[qp * 32 + l31];
        const float inv  = ltot > 0.0f ? 1.0f / ltot : 0.0f;
        #pragma unroll
        for (int r = 0; r < 16; ++r) {
            const int qloc = (r & 3) + 8 * (r >> 2) + 4 * hi2;
            const float invr = __shfl(inv, qloc, 64);
            const int qg = qt * 64 + qp * 32 + qloc;
            const long obase = ((long)b * SEQ + qg) * HDIM + h * 64 + l31;
            const float o0 = oacc0[r] + cmbO[(qp * 32 + qloc) * 64 + l31];
            const float o1 = oacc1[r] + cmbO[(qp * 32 + qloc) * 64 + 32 + l31];
            Ob[obase]      = f2bf(o0 * invr);
            Ob[obase + 32] = f2bf(o1 * invr);
        }
    }
}

// ---------------- host launch ----------------
extern "C" void kernel_launch(void* const* d_in, const int* in_sizes, int n_in,
                              void* d_out, int out_size, void* d_ws, size_t ws_size,
                              hipStream_t stream) {
    const float* q    = (const float*)d_in[0];
    const float* k    = (const float*)d_in[1];
    const float* v    = (const float*)d_in[2];
    const void*  mask = d_in[3];
    const float* rel  = (const float*)d_in[4];
    const float* Wq   = (const float*)d_in[5];
    const float* bq   = (const float*)d_in[6];
    const float* Wk   = (const float*)d_in[7];
    const float* bk   = (const float*)d_in[8];
    const float* Wv   = (const float*)d_in[9];
    const float* bv   = (const float*)d_in[10];
    const float* Wo   = (const float*)d_in[11];
    const float* bo   = (const float*)d_in[12];
    (void)in_sizes; (void)n_in; (void)out_size; (void)ws_size;

    char* ws = (char*)d_ws;
    size_t off = 0;
    auto alloc = [&](size_t bytes) {
        char* p = ws + off;
        off += (bytes + 255) & ~(size_t)255;
        return p;
    };
    const size_t xBytes = (size_t)MROWS * HDIM * 2;      // 8 MB bf16
    const size_t wBytes = (size_t)HDIM * HDIM * 2;       // 2 MB bf16
    const size_t poolBytes = 3 * xBytes + 3 * wBytes;    // 30 MB (>= rT's 16 MB)

    // persistent region
    short* Qb  = (short*)alloc(xBytes);
    short* Kb  = (short*)alloc(xBytes);
    short* Vt  = (short*)alloc(xBytes);
    short* wob = (short*)alloc(wBytes);
    int*   flag = (int*)alloc(256);
    // pool: phase 1 = xq,xk,xv,wqb,wkb,wvb; phase 2 = rT (16 MB)
    char* pool = (char*)alloc(poolBytes);
    short* Ab  = (short*)alloc(xBytes);

    short* xq  = (short*)(pool);
    short* xk  = (short*)(pool + xBytes);
    short* xv  = (short*)(pool + 2 * xBytes);
    short* wqb = (short*)(pool + 3 * xBytes);
    short* wkb = (short*)(pool + 3 * xBytes + wBytes);
    short* wvb = (short*)(pool + 3 * xBytes + 2 * wBytes);
    short* rT  = (short*)(pool);

    const int n4x = MROWS * HDIM / 4, n4w = HDIM * HDIM / 4;
    cvt_all_kernel<<<2048, 256, 0, stream>>>(q, k, v, Wq, Wk, Wv, Wo,
                                             xq, xk, xv, wqb, wkb, wvb, wob, n4x, n4w);
    detect_mask_kernel<<<1, 256, 0, stream>>>((const unsigned int*)mask, flag);

    qkv_gemm<<<768, 256, 0, stream>>>(xq, xk, xv, wqb, wkb, wvb,
                                      bq, bk, bv, Qb, Kb, Vt);

    // pool is dead for x/w now; build rT over it
    fuse_rel_kernel<<<512, 256, 0, stream>>>(rel, mask, flag, rT);

    attn_fwd<<<1024, 256, 0, stream>>>(Qb, Kb, Vt, rT, Ab);

    out_gemm<<<512, 256, 0, stream>>>(Ab, wob, bo, (float*)d_out);
}